// Round 2
// 466.081 us; speedup vs baseline: 1.0461x; 1.0461x over previous
//
#include <hip/hip_runtime.h>
#include <stdint.h>

#define Bx 64
#define Tx 2048
#define ENCx 512
#define ATTx 256

typedef float f4 __attribute__((ext_vector_type(4)));
typedef float f32x4 __attribute__((ext_vector_type(4)));
typedef short bf16x8 __attribute__((ext_vector_type(8)));
typedef __fp16 h2 __attribute__((ext_vector_type(2)));

__device__ __forceinline__ unsigned short f2bf(float f) {
  union { float f; uint32_t u; } c; c.f = f;
  uint32_t u = c.u;
  u += 0x7fffu + ((u >> 16) & 1u);   // RNE
  return (unsigned short)(u >> 16);
}

// pack two floats -> bf16 pair (round-to-nearest via +0x8000, then v_perm)
__device__ __forceinline__ uint32_t pk_bf(float lo, float hi) {
  uint32_t a = __float_as_uint(lo) + 0x8000u;
  uint32_t b = __float_as_uint(hi) + 0x8000u;
  return __builtin_amdgcn_perm(b, a, 0x07060302u);  // {hi16(b), hi16(a)}
}

// pack two floats -> f16 pair (v_cvt_pkrtz_f16_f32)
__device__ __forceinline__ uint32_t pk_f16(float lo, float hi) {
  h2 r = __builtin_amdgcn_cvt_pkrtz(lo, hi);
  union { h2 h; uint32_t u; } c; c.h = r;
  return c.u;
}

__device__ __forceinline__ float ftanh(float x) {
  x = fminf(8.f, fmaxf(-8.f, x));
  float z = __expf(2.f * x);
  return 1.f - __fdividef(2.f, z + 1.f);
}

// K0: pack W_enc -> bf16, transposed + chunk-contiguous:
// WTc[(kc*256 + n)*32 + kk] = bf16(W_enc[(kc*32+kk)*256 + n])
__global__ void k0_wt(const float* __restrict__ W, unsigned short* __restrict__ WTc) {
  int tid = blockIdx.x * 256 + threadIdx.x;   // 131072 total
  int kc = tid >> 13;
  int r = tid & 8191;
  int n = r >> 5;
  int kk = r & 31;
  WTc[tid] = f2bf(W[(kc * 32 + kk) * ATTx + n]);
}

// K1: pd[b][a] = dec_hidden[b,:] @ W_dec[:,a]  (fp32)
__global__ void k1_pd(const float* __restrict__ dec, const float* __restrict__ Wd,
                      float* __restrict__ pd) {
  __shared__ float ld[512];
  int b = blockIdx.x, a = threadIdx.x;
  ld[a] = dec[b * 512 + a];
  ld[a + 256] = dec[b * 512 + a + 256];
  __syncthreads();
  float s = 0.f;
#pragma unroll 8
  for (int d = 0; d < 512; ++d) s = fmaf(ld[d], Wd[d * ATTx + a], s);
  pd[b * ATTx + a] = s;
}

// K2 (fused): per 64-row chunk:
//   energy[m] = v . tanh(enc[m,:] @ W_enc + pd[b,:])   (barrier-free MFMA loop)
//   + stage enc tile to LDS as f16 (XOR-swizzled) during the loop
//   + chunk-local softmax partials m_loc/l_loc and
//     part[chunk][b][e] = sum_t exp(e_t - m_loc) * enc[t,e]
// 2048 blocks x 128 threads (2 waves x 32 rows). enc read from HBM ONCE.
__global__ __launch_bounds__(128, 1) void k2_fused(
    const float* __restrict__ enc, const unsigned short* __restrict__ WTc,
    const float* __restrict__ pd, const float* __restrict__ v,
    const int* __restrict__ mask, float* __restrict__ energy,
    float* __restrict__ part, float* __restrict__ mloc, float* __restrict__ lloc) {
  __shared__ float pdv[256];
  __shared__ float vvs[256];
  __shared__ unsigned short enc_s[64 * 512];   // f16 tile, 64 KB, swizzled
  __shared__ float e_lds[64];
  __shared__ float wl[64];

  const int tid = threadIdx.x;
  const int wid = tid >> 6;        // 0..1
  const int lane = tid & 63;
  const int q = lane >> 4;         // k-quad
  const int c15 = lane & 15;       // row (A) / col (B,C)
  const int m0 = blockIdx.x * 64;  // 64 rows per block
  const int b = m0 >> 11;          // batch (64 | 2048)
  const int chunk = blockIdx.x & 31;

  pdv[tid] = pd[b * ATTx + tid];
  pdv[tid + 128] = pd[b * ATTx + tid + 128];
  vvs[tid] = v[tid];
  vvs[tid + 128] = v[tid + 128];
  __syncthreads();

  const int r0 = wid * 32 + c15;   // local row for mt=0 (mt=1 -> r0+16)
  const int mrow = m0 + r0;
  const float* a0p = enc + (size_t)mrow * ENCx + q * 8;
  const float* a1p = a0p + 16 * ENCx;
  const unsigned short* wb = WTc + c15 * 32 + q * 8;

  uint4* enc16 = (uint4*)enc_s;
  const int sw = r0 & 7;                    // same for r0+16
  const int w0base = r0 * 64 + q;           // 16B-index base (kc adds 4*kc)
  const int w1base = (r0 + 16) * 64 + q;

  f32x4 acc[2][16];
#pragma unroll
  for (int mt = 0; mt < 2; ++mt)
#pragma unroll
    for (int ct = 0; ct < 16; ++ct) { f32x4 z = {0.f,0.f,0.f,0.f}; acc[mt][ct] = z; }

  // prologue: enc slice kc=0
  f4 x0 = *(const f4*)(a0p);
  f4 x1 = *(const f4*)(a0p + 4);
  f4 y0 = *(const f4*)(a1p);
  f4 y1 = *(const f4*)(a1p + 4);

  for (int kc = 0; kc < 16; ++kc) {
    // B fragments for kc from L2-resident packed WTc
    bf16x8 bfr[16];
    const unsigned short* wkc = wb + kc * 8192;
#pragma unroll
    for (int ct = 0; ct < 16; ++ct)
      bfr[ct] = *(const bf16x8*)(wkc + ct * 512);

    // prefetch next enc slice (HBM latency hidden under this kc's MFMA)
    const int kn = (kc < 15) ? kc + 1 : 15;
    f4 nx0 = *(const f4*)(a0p + kn * 32);
    f4 nx1 = *(const f4*)(a0p + kn * 32 + 4);
    f4 ny0 = *(const f4*)(a1p + kn * 32);
    f4 ny1 = *(const f4*)(a1p + kn * 32 + 4);

    // stage current enc slice to LDS as f16 (swizzled, conflict-free)
    uint4 hp0, hp1;
    hp0.x = pk_f16(x0.x, x0.y); hp0.y = pk_f16(x0.z, x0.w);
    hp0.z = pk_f16(x1.x, x1.y); hp0.w = pk_f16(x1.z, x1.w);
    hp1.x = pk_f16(y0.x, y0.y); hp1.y = pk_f16(y0.z, y0.w);
    hp1.z = pk_f16(y1.x, y1.y); hp1.w = pk_f16(y1.z, y1.w);
    enc16[(w0base + kc * 4) ^ sw] = hp0;
    enc16[(w1base + kc * 4) ^ sw] = hp1;

    // A fragments -> bf16, MFMA
    union { uint32_t u[4]; bf16x8 v; } am0, am1;
    am0.u[0] = pk_bf(x0.x, x0.y); am0.u[1] = pk_bf(x0.z, x0.w);
    am0.u[2] = pk_bf(x1.x, x1.y); am0.u[3] = pk_bf(x1.z, x1.w);
    am1.u[0] = pk_bf(y0.x, y0.y); am1.u[1] = pk_bf(y0.z, y0.w);
    am1.u[2] = pk_bf(y1.x, y1.y); am1.u[3] = pk_bf(y1.z, y1.w);

#pragma unroll
    for (int ct = 0; ct < 16; ++ct) {
      acc[0][ct] = __builtin_amdgcn_mfma_f32_16x16x32_bf16(am0.v, bfr[ct], acc[0][ct], 0, 0, 0);
      acc[1][ct] = __builtin_amdgcn_mfma_f32_16x16x32_bf16(am1.v, bfr[ct], acc[1][ct], 0, 0, 0);
    }
    x0 = nx0; x1 = nx1; y0 = ny0; y1 = ny1;
  }

  // energy epilogue: C/D layout col = c15, row = q*4 + i (within 16x16 tile)
  float ps[2][4];
#pragma unroll
  for (int mt = 0; mt < 2; ++mt)
#pragma unroll
    for (int i = 0; i < 4; ++i) ps[mt][i] = 0.f;
#pragma unroll
  for (int ct = 0; ct < 16; ++ct) {
    float pv = pdv[ct * 16 + c15];
    float vv = vvs[ct * 16 + c15];
#pragma unroll
    for (int mt = 0; mt < 2; ++mt)
#pragma unroll
      for (int i = 0; i < 4; ++i)
        ps[mt][i] += ftanh(acc[mt][ct][i] + pv) * vv;
  }
#pragma unroll
  for (int s = 1; s < 16; s <<= 1)
#pragma unroll
    for (int mt = 0; mt < 2; ++mt)
#pragma unroll
      for (int i = 0; i < 4; ++i)
        ps[mt][i] += __shfl_xor(ps[mt][i], s, 64);
  if (c15 == 0) {
#pragma unroll
    for (int mt = 0; mt < 2; ++mt)
#pragma unroll
      for (int i = 0; i < 4; ++i) {
        int lr = wid * 32 + mt * 16 + q * 4 + i;
        int gm = m0 + lr;
        float ev = mask[gm] ? -1e30f : ps[mt][i];
        energy[gm] = ev;
        e_lds[lr] = ev;
      }
  }
  __syncthreads();

  // chunk-local softmax partials (each wave computes redundantly over all 64 rows)
  float ev = e_lds[lane];
  float mx = ev;
#pragma unroll
  for (int s = 1; s < 64; s <<= 1) mx = fmaxf(mx, __shfl_xor(mx, s, 64));
  float w = (ev < -1e29f) ? 0.f : __expf(ev - mx);  // masked rows -> 0
  float ls = w;
#pragma unroll
  for (int s = 1; s < 64; s <<= 1) ls += __shfl_xor(ls, s, 64);
  if (wid == 0) wl[lane] = w;
  if (tid == 0) { mloc[b * 32 + chunk] = mx; lloc[b * 32 + chunk] = ls; }
  __syncthreads();

  // context partial from LDS f16 tile: part[chunk][b][e] = sum_t w[t]*enc[t][e]
  const uint32_t* encu = (const uint32_t*)enc_s;
  float a0 = 0.f, a1 = 0.f, a2 = 0.f, a3 = 0.f;
#pragma unroll 4
  for (int t = 0; t < 64; ++t) {
    float wv = wl[t];
    int xr = (t & 7) << 2;
    uint32_t p0 = encu[(t * 256 + tid) ^ xr];
    uint32_t p1 = encu[(t * 256 + tid + 128) ^ xr];
    union { uint32_t u; h2 h; } c0, c1;
    c0.u = p0; c1.u = p1;
    a0 = fmaf((float)c0.h.x, wv, a0);
    a1 = fmaf((float)c0.h.y, wv, a1);
    a2 = fmaf((float)c1.h.x, wv, a2);
    a3 = fmaf((float)c1.h.y, wv, a3);
  }
  float* pp = part + (size_t)(chunk * 64 + b) * 512;
  float2 s0; s0.x = a0; s0.y = a1;
  float2 s1; s1.x = a2; s1.y = a3;
  *(float2*)(pp + 2 * tid) = s0;
  *(float2*)(pp + 2 * tid + 256) = s1;
}

// K3 (fused): phase A = per-b softmax over T (attn output, dead-row -> 0);
//             phase B = merge 32 chunk partials with rescale -> ctx
__global__ void k3_merge(const float* __restrict__ energy, const float* __restrict__ part,
                         const float* __restrict__ mloc, const float* __restrict__ lloc,
                         float* __restrict__ attn, float* __restrict__ ctx) {
  __shared__ float redm[4];
  __shared__ float redl[4];
  __shared__ float sc[32];
  int b = blockIdx.x, tid = threadIdx.x;
  int lane = tid & 63, wid = tid >> 6;

  // ---- phase A: softmax (unchanged semantics) ----
  float e[8];
#pragma unroll
  for (int i = 0; i < 8; ++i) e[i] = energy[b * Tx + tid + i * 256];
  float m = e[0];
#pragma unroll
  for (int i = 1; i < 8; ++i) m = fmaxf(m, e[i]);
#pragma unroll
  for (int s = 1; s < 64; s <<= 1) m = fmaxf(m, __shfl_xor(m, s, 64));
  if (lane == 0) redm[wid] = m;
  __syncthreads();
  m = fmaxf(fmaxf(redm[0], redm[1]), fmaxf(redm[2], redm[3]));
  bool dead = (m < -1e29f);
  float w[8];
  float l = 0.f;
#pragma unroll
  for (int i = 0; i < 8; ++i) { w[i] = dead ? 0.f : __expf(e[i] - m); l += w[i]; }
#pragma unroll
  for (int s = 1; s < 64; s <<= 1) l += __shfl_xor(l, s, 64);
  if (lane == 0) redl[wid] = l;
  __syncthreads();
  l = redl[0] + redl[1] + redl[2] + redl[3];
  float inv = dead ? 0.f : __fdividef(1.f, l);
#pragma unroll
  for (int i = 0; i < 8; ++i) attn[b * Tx + tid + i * 256] = w[i] * inv;

  // ---- phase B: merge chunk partials ----
  if (tid < 64) {
    float mc = (lane < 32) ? mloc[b * 32 + lane] : -3e38f;
    float lc = (lane < 32) ? lloc[b * 32 + lane] : 0.f;
    float mg = mc;
#pragma unroll
    for (int s = 1; s < 64; s <<= 1) mg = fmaxf(mg, __shfl_xor(mg, s, 64));
    float sl = (lane < 32) ? lc * __expf(mc - mg) : 0.f;
    float lg = sl;
#pragma unroll
    for (int s = 1; s < 64; s <<= 1) lg += __shfl_xor(lg, s, 64);
    float ig = (lg > 0.f) ? __fdividef(1.f, lg) : 0.f;   // fully-masked b -> 0
    if (lane < 32) sc[lane] = __expf(mc - mg) * ig;
  }
  __syncthreads();
  float2 a; a.x = 0.f; a.y = 0.f;
  const float* pb = part + (size_t)b * 512 + tid * 2;
#pragma unroll 8
  for (int c = 0; c < 32; ++c) {
    float2 p = *(const float2*)(pb + (size_t)c * 64 * 512);
    float s = sc[c];
    a.x = fmaf(p.x, s, a.x);
    a.y = fmaf(p.y, s, a.y);
  }
  *(float2*)(ctx + b * 512 + tid * 2) = a;
}

extern "C" void kernel_launch(void* const* d_in, const int* in_sizes, int n_in,
                              void* d_out, int out_size, void* d_ws, size_t ws_size,
                              hipStream_t stream) {
  const float* enc   = (const float*)d_in[0];
  const float* dec   = (const float*)d_in[1];
  const int*   mask  = (const int*)d_in[2];
  const float* W_enc = (const float*)d_in[3];
  const float* W_dec = (const float*)d_in[4];
  const float* v     = (const float*)d_in[5];
  float* ctx  = (float*)d_out;          // [64,512]
  float* attn = ctx + Bx * ENCx;        // [64,2048]
  char* ws = (char*)d_ws;
  unsigned short* WTc = (unsigned short*)ws;                   // 262144 B
  float* pd     = (float*)(ws + 262144);                       // 65536 B
  float* energy = (float*)(ws + 262144 + 65536);               // 524288 B
  float* part   = (float*)(ws + 851968);                       // 32*64*512*4 = 4 MB
  float* mloc   = (float*)(ws + 851968 + 4194304);             // 8 KB
  float* lloc   = (float*)(ws + 851968 + 4194304 + 8192);      // 8 KB

  k0_wt<<<512, 256, 0, stream>>>(W_enc, WTc);
  k1_pd<<<64, 256, 0, stream>>>(dec, W_dec, pd);
  k2_fused<<<2048, 128, 0, stream>>>(enc, WTc, pd, v, mask, energy, part, mloc, lloc);
  k3_merge<<<64, 256, 0, stream>>>(energy, part, mloc, lloc, attn, ctx);
}